// Round 17
// baseline (241.980 us; speedup 1.0000x reference)
//
#include <hip/hip_runtime.h>
#include <hip/hip_bf16.h>

#define HH 32
#define DD 128
#define HD (HH*DD)          // 4096
#define NFILL 2048
#define FLEN 512
#define SCALE_F 0.08838834764831845f
#define NEGINF (-1e30f)
#define PSTRIDE 136         // floats per partial record: [m, l, pad..., acc[128]]

typedef short bf16x8 __attribute__((ext_vector_type(8)));
typedef float f32x4 __attribute__((ext_vector_type(4)));

__device__ __forceinline__ short f2bf(float x) {
    union { float f; unsigned u; } c; c.f = x;
    unsigned u = c.u;
    u += 0x7FFFu + ((u >> 16) & 1u);   // RNE
    return (short)(u >> 16);
}

__device__ __forceinline__ bf16x8 load8_bf16(const float* __restrict__ p) {
    float4 a = *(const float4*)p;
    float4 b = *(const float4*)(p + 4);
    bf16x8 r;
    r[0]=f2bf(a.x); r[1]=f2bf(a.y); r[2]=f2bf(a.z); r[3]=f2bf(a.w);
    r[4]=f2bf(b.x); r[5]=f2bf(b.y); r[6]=f2bf(b.z); r[7]=f2bf(b.w);
    return r;
}

// ======================= GEN v6: wave-contiguous 1KB bursts + NT =======================
// 1024 blocks x 256 thr: g=bid>>6, pc=bid&63 (16-position chunk = ONE block-table entry).
// Wave wv = head-quarter (8 heads); lane: head=wv*8+(lane>>3), d=(lane&7)*16..+15.
// One wave-wide load = 64 lanes x 16B = 1KB contiguous; block covers the full 16KB span.
// Depth-2 named pipeline, NT loads, no LDS/barriers; per-wave partial records.
#define LOADP(S, i) do { \
    const float* _kb = kb0 + (long)(i) * HD; \
    const float* _vb = vb0 + (long)(i) * HD; \
    S##k0 = __builtin_nontemporal_load((const f32x4*)_kb); \
    S##k1 = __builtin_nontemporal_load((const f32x4*)(_kb + 4)); \
    S##k2 = __builtin_nontemporal_load((const f32x4*)(_kb + 8)); \
    S##k3 = __builtin_nontemporal_load((const f32x4*)(_kb + 12)); \
    S##v0 = __builtin_nontemporal_load((const f32x4*)_vb); \
    S##v1 = __builtin_nontemporal_load((const f32x4*)(_vb + 4)); \
    S##v2 = __builtin_nontemporal_load((const f32x4*)(_vb + 8)); \
    S##v3 = __builtin_nontemporal_load((const f32x4*)(_vb + 12)); \
} while (0)

#define COMPUTEP(S, i) do { \
    float dot = S##k0[0]*qv[0]  + S##k0[1]*qv[1]  + S##k0[2]*qv[2]  + S##k0[3]*qv[3] \
              + S##k1[0]*qv[4]  + S##k1[1]*qv[5]  + S##k1[2]*qv[6]  + S##k1[3]*qv[7] \
              + S##k2[0]*qv[8]  + S##k2[1]*qv[9]  + S##k2[2]*qv[10] + S##k2[3]*qv[11] \
              + S##k3[0]*qv[12] + S##k3[1]*qv[13] + S##k3[2]*qv[14] + S##k3[3]*qv[15]; \
    dot += __shfl_xor(dot, 1); \
    dot += __shfl_xor(dot, 2); \
    dot += __shfl_xor(dot, 4); \
    float s = dot * SCALE_F; \
    if (p0 + (i) == ctxm1) s = NEGINF;   /* stale slot: mask (wave-uniform) */ \
    const float mn = fmaxf(m, s); \
    const float sc = __expf(m - mn); \
    const float pw = __expf(s - mn); \
    lsum = lsum * sc + pw; \
    o[0]  = o[0]*sc  + pw*S##v0[0];  o[1]  = o[1]*sc  + pw*S##v0[1]; \
    o[2]  = o[2]*sc  + pw*S##v0[2];  o[3]  = o[3]*sc  + pw*S##v0[3]; \
    o[4]  = o[4]*sc  + pw*S##v1[0];  o[5]  = o[5]*sc  + pw*S##v1[1]; \
    o[6]  = o[6]*sc  + pw*S##v1[2];  o[7]  = o[7]*sc  + pw*S##v1[3]; \
    o[8]  = o[8]*sc  + pw*S##v2[0];  o[9]  = o[9]*sc  + pw*S##v2[1]; \
    o[10] = o[10]*sc + pw*S##v2[2];  o[11] = o[11]*sc + pw*S##v2[3]; \
    o[12] = o[12]*sc + pw*S##v3[0];  o[13] = o[13]*sc + pw*S##v3[1]; \
    o[14] = o[14]*sc + pw*S##v3[2];  o[15] = o[15]*sc + pw*S##v3[3]; \
    m = mn; \
} while (0)

#define SBAR __builtin_amdgcn_sched_barrier(0)

__global__ __launch_bounds__(256, 1)
void gen_kernel(const float* __restrict__ q, const float* __restrict__ k,
                const float* __restrict__ v, const float* __restrict__ kc,
                const float* __restrict__ vc, const int* __restrict__ btab,
                const int* __restrict__ ctxlens, float* __restrict__ ws)
{
    const int bid  = blockIdx.x;
    const int g    = bid >> 6;
    const int pc   = bid & 63;
    const int tid  = threadIdx.x;
    const int wv   = tid >> 6;       // head-quarter
    const int lane = tid & 63;
    const int hl   = lane >> 3;      // head-in-quarter 0..7
    const int ctx  = ctxlens[g];
    const int ctxm1 = ctx - 1;
    const int p0   = pc * 16;

    const long blk = btab[g * 64 + pc];          // wave-uniform scalar
    const long off = wv * 1024 + lane * 16;      // h*128 + (lane&7)*16
    const float* kb0 = kc + blk * 16 * HD + off;
    const float* vb0 = vc + blk * 16 * HD + off;

    const long freshoff = (long)(NFILL + g) * HD + off;
    float qv[16];
    {
        const float* qp = q + freshoff;
        float4 a0 = *(const float4*)qp,       a1 = *(const float4*)(qp + 4);
        float4 a2 = *(const float4*)(qp + 8), a3 = *(const float4*)(qp + 12);
        qv[0]=a0.x; qv[1]=a0.y; qv[2]=a0.z;  qv[3]=a0.w;
        qv[4]=a1.x; qv[5]=a1.y; qv[6]=a1.z;  qv[7]=a1.w;
        qv[8]=a2.x; qv[9]=a2.y; qv[10]=a2.z; qv[11]=a2.w;
        qv[12]=a3.x; qv[13]=a3.y; qv[14]=a3.z; qv[15]=a3.w;
    }

    float m = NEGINF, lsum = 0.f;
    float o[16];
    #pragma unroll
    for (int j = 0; j < 16; ++j) o[j] = 0.f;

    f32x4 Ak0,Ak1,Ak2,Ak3,Av0,Av1,Av2,Av3;
    f32x4 Bk0,Bk1,Bk2,Bk3,Bv0,Bv1,Bv2,Bv3;

    LOADP(A, 0); LOADP(B, 1); SBAR;
    #pragma unroll
    for (int i = 0; i < 16; i += 2) {
        COMPUTEP(A, i);
        if (i + 2 < 16) { LOADP(A, i + 2); } SBAR;
        COMPUTEP(B, i + 1);
        if (i + 3 < 16) { LOADP(B, i + 3); } SBAR;
    }

    // fresh token (position ctx-1) from k/v — wave-uniform, after the loop
    if (ctxm1 >= p0 && ctxm1 < p0 + 16) {
        const float* _kb = k + freshoff;
        const float* _vb = v + freshoff;
        f32x4 Fk0 = *(const f32x4*)_kb,       Fk1 = *(const f32x4*)(_kb + 4);
        f32x4 Fk2 = *(const f32x4*)(_kb + 8), Fk3 = *(const f32x4*)(_kb + 12);
        f32x4 Fv0 = *(const f32x4*)_vb,       Fv1 = *(const f32x4*)(_vb + 4);
        f32x4 Fv2 = *(const f32x4*)(_vb + 8), Fv3 = *(const f32x4*)(_vb + 12);
        float dot = Fk0[0]*qv[0]  + Fk0[1]*qv[1]  + Fk0[2]*qv[2]  + Fk0[3]*qv[3]
                  + Fk1[0]*qv[4]  + Fk1[1]*qv[5]  + Fk1[2]*qv[6]  + Fk1[3]*qv[7]
                  + Fk2[0]*qv[8]  + Fk2[1]*qv[9]  + Fk2[2]*qv[10] + Fk2[3]*qv[11]
                  + Fk3[0]*qv[12] + Fk3[1]*qv[13] + Fk3[2]*qv[14] + Fk3[3]*qv[15];
        dot += __shfl_xor(dot, 1);
        dot += __shfl_xor(dot, 2);
        dot += __shfl_xor(dot, 4);
        const float s  = dot * SCALE_F;
        const float mn = fmaxf(m, s);
        const float sc = __expf(m - mn);
        const float pw = __expf(s - mn);
        lsum = lsum * sc + pw;
        o[0]  = o[0]*sc  + pw*Fv0[0];  o[1]  = o[1]*sc  + pw*Fv0[1];
        o[2]  = o[2]*sc  + pw*Fv0[2];  o[3]  = o[3]*sc  + pw*Fv0[3];
        o[4]  = o[4]*sc  + pw*Fv1[0];  o[5]  = o[5]*sc  + pw*Fv1[1];
        o[6]  = o[6]*sc  + pw*Fv1[2];  o[7]  = o[7]*sc  + pw*Fv1[3];
        o[8]  = o[8]*sc  + pw*Fv2[0];  o[9]  = o[9]*sc  + pw*Fv2[1];
        o[10] = o[10]*sc + pw*Fv2[2];  o[11] = o[11]*sc + pw*Fv2[3];
        o[12] = o[12]*sc + pw*Fv3[0];  o[13] = o[13]*sc + pw*Fv3[1];
        o[14] = o[14]*sc + pw*Fv3[2];  o[15] = o[15]*sc + pw*Fv3[3];
        m = mn;
    }

    // ---- direct per-wave partial write: record (g, h = wv*8+hl, pc) ----
    {
        const int h   = wv * 8 + hl;
        const int dl  = (lane & 7) * 16;
        const long rec = ((long)(g * 32 + h) * 64 + pc) * PSTRIDE;
        #pragma unroll
        for (int t = 0; t < 4; ++t)
            *(float4*)(ws + rec + 8 + dl + 4 * t) = make_float4(o[4*t], o[4*t+1], o[4*t+2], o[4*t+3]);
        if ((lane & 7) == 0) { ws[rec] = m; ws[rec + 1] = lsum; }
    }
}

// ======================= MERGE: 64 chunk-partials per (g,h) =======================
__global__ __launch_bounds__(256)
void merge_kernel(const float* __restrict__ ws, float* __restrict__ out)
{
    const int idx = blockIdx.x * 256 + threadIdx.x;   // 65536
    const int gh  = idx >> 7;       // 0..511
    const int d   = idx & 127;
    const int g   = gh >> 5;
    const int h   = gh & 31;
    float M = NEGINF;
    #pragma unroll 8
    for (int c = 0; c < 64; ++c)
        M = fmaxf(M, ws[((long)gh * 64 + c) * PSTRIDE]);
    float L = 0.f, num = 0.f;
    #pragma unroll 8
    for (int c = 0; c < 64; ++c) {
        const long rec = ((long)gh * 64 + c) * PSTRIDE;
        const float e = __expf(ws[rec] - M);
        L   += e * ws[rec + 1];
        num += e * ws[rec + 8 + d];
    }
    out[(long)(NFILL + g) * 4096 + h * DD + d] = num / L;
}

// ======================= FILL v4 (r9 known-good, unchanged) =======================
struct QS {
    bf16x8 qf[4];
    float  mrow[4], lsum[4];
    f32x4  o[8];
};

__device__ __forceinline__ void qs_init(QS& S, const float* qbase, int g16) {
    #pragma unroll
    for (int c = 0; c < 4; ++c) S.qf[c] = load8_bf16(qbase + c * 32 + g16 * 8);
    #pragma unroll
    for (int r = 0; r < 4; ++r) { S.mrow[r] = NEGINF; S.lsum[r] = 0.f; }
    #pragma unroll
    for (int n = 0; n < 8; ++n) { S.o[n][0]=0.f; S.o[n][1]=0.f; S.o[n][2]=0.f; S.o[n][3]=0.f; }
}

__device__ __forceinline__ void qs_tile(QS& S, int qt, int k0,
                                        const char* Kl, const char* Vt2,
                                        char* pbase, int g16, int li) {
    f32x4 sA; sA[0]=0.f; sA[1]=0.f; sA[2]=0.f; sA[3]=0.f;
    f32x4 sB; sB[0]=0.f; sB[1]=0.f; sB[2]=0.f; sB[3]=0.f;
    #pragma unroll
    for (int c = 0; c < 4; ++c) {
        const int rA = li, rB = li + 16;
        bf16x8 kfA = *(const bf16x8*)(Kl + ((rA * 256 + c * 64 + g16 * 16) ^ ((rA & 7) << 4)));
        bf16x8 kfB = *(const bf16x8*)(Kl + ((rB * 256 + c * 64 + g16 * 16) ^ ((rB & 7) << 4)));
        sA = __builtin_amdgcn_mfma_f32_16x16x32_bf16(S.qf[c], kfA, sA, 0, 0, 0);
        sB = __builtin_amdgcn_mfma_f32_16x16x32_bf16(S.qf[c], kfB, sB, 0, 0, 0);
    }
    float pA[4], pB[4], corr[4];
    #pragma unroll
    for (int r = 0; r < 4; ++r) {
        const int qrow = qt * 16 + g16 * 4 + r;
        float a  = (k0 + li      <= qrow) ? sA[r] * SCALE_F : NEGINF;
        float bb = (k0 + 16 + li <= qrow) ? sB[r] * SCALE_F : NEGINF;
        float rm = fmaxf(a, bb);
        #pragma unroll
        for (int off = 1; off < 16; off <<= 1) rm = fmaxf(rm, __shfl_xor(rm, off));
        const float mn = fmaxf(S.mrow[r], rm);
        corr[r] = __expf(S.mrow[r] - mn);
        pA[r] = __expf(a  - mn);
        pB[r] = __expf(bb - mn);
        float rs = pA[r] + pB[r];
        #pragma unroll
        for (int off = 1; off < 16; off <<= 1) rs += __shfl_xor(rs, off);
        S.lsum[r] = S.lsum[r] * corr[r] + rs;
        S.mrow[r] = mn;
    }
    #pragma unroll
    for (int n = 0; n < 8; ++n)
        #pragma unroll
        for (int r = 0; r < 4; ++r) S.o[n][r] *= corr[r];

    #pragma unroll
    for (int r = 0; r < 4; ++r) {
        const int row = g16 * 4 + r;
        const int xo  = (row & 3) << 4;
        *(short*)(pbase + ((row * 64 + li * 2     ) ^ xo)) = f2bf(pA[r]);
        *(short*)(pbase + ((row * 64 + 32 + li * 2) ^ xo)) = f2bf(pB[r]);
    }
    asm volatile("s_waitcnt lgkmcnt(0)" ::: "memory");
    __builtin_amdgcn_sched_barrier(0);
    bf16x8 pa = *(const bf16x8*)(pbase + ((li * 64 + g16 * 16) ^ ((li & 3) << 4)));

    #pragma unroll
    for (int n = 0; n < 8; ++n) {
        bf16x8 vf = *(const bf16x8*)(Vt2 + (n * 1024 + g16 * 256 + li * 16));
        S.o[n] = __builtin_amdgcn_mfma_f32_16x16x32_bf16(pa, vf, S.o[n], 0, 0, 0);
    }
}

__device__ __forceinline__ void qs_out(QS& S, int qt, int b, int h, int g16, int li,
                                       float* __restrict__ out) {
    float inv[4];
    #pragma unroll
    for (int r = 0; r < 4; ++r) inv[r] = 1.f / S.lsum[r];
    #pragma unroll
    for (int n = 0; n < 8; ++n) {
        #pragma unroll
        for (int r = 0; r < 4; ++r) {
            const int t = b * FLEN + qt * 16 + g16 * 4 + r;
            out[(long)t * 4096 + h * DD + n * 16 + li] = S.o[n][r] * inv[r];
        }
    }
}

__global__ __launch_bounds__(512, 2)
void fill_kernel(const float* __restrict__ q, const float* __restrict__ k,
                 const float* __restrict__ v, float* __restrict__ out)
{
    __shared__ short Kl[32 * 128];
    __shared__ short Vt2[8 * 4 * 16 * 8];
    __shared__ short plds[8][16][32];

    const int bid = blockIdx.x;
    const int b   = bid >> 6;
    const int h   = (bid >> 1) & 31;
    const int jh  = bid & 1;
    const int tid  = threadIdx.x;
    const int wv   = tid >> 6;
    const int lane = tid & 63;
    const int g16  = lane >> 4;
    const int li   = lane & 15;

    const int qtA = 2 * wv + jh;
    const int qtB = qtA + 16;
    const int npA = wv + 1;
    const int npB = wv + 9;

    QS SA, SB2;
    qs_init(SA,  q + ((long)(b * FLEN + qtA * 16 + li) * HH + h) * DD, g16);
    qs_init(SB2, q + ((long)(b * FLEN + qtB * 16 + li) * HH + h) * DD, g16);

    const int spos = tid >> 4;
    const int sd8  = tid & 15;
    const int vd   = tid & 127;
    const int voct = tid >> 7;

    char* pbase = (char*)&plds[wv][0][0];

    for (int kp = 0; kp < 16; ++kp) {
        const int k0 = kp * 32;
        {
            const float* src = k + ((long)(b * FLEN + k0 + spos) * HH + h) * DD + sd8 * 8;
            bf16x8 w = load8_bf16(src);
            const int base = spos * 256 + sd8 * 16;
            *(bf16x8*)((char*)Kl + (base ^ ((spos & 7) << 4))) = w;
        }
        {
            const float* src = v + ((long)(b * FLEN + k0 + voct * 8) * HH + h) * DD + vd;
            bf16x8 w;
            #pragma unroll
            for (int jj = 0; jj < 8; ++jj)
                w[jj] = f2bf(src[(long)jj * HD]);
            *(bf16x8*)((char*)Vt2 + ((vd >> 4) * 1024 + voct * 256 + (vd & 15) * 16)) = w;
        }
        __syncthreads();

        if (kp < npA) qs_tile(SA,  qtA, k0, (const char*)Kl, (const char*)Vt2, pbase, g16, li);
        if (kp < npB) qs_tile(SB2, qtB, k0, (const char*)Kl, (const char*)Vt2, pbase, g16, li);

        __syncthreads();
    }

    qs_out(SA,  qtA, b, h, g16, li, out);
    qs_out(SB2, qtB, b, h, g16, li, out);
}

extern "C" void kernel_launch(void* const* d_in, const int* in_sizes, int n_in,
                              void* d_out, int out_size, void* d_ws, size_t ws_size,
                              hipStream_t stream) {
    const float* q  = (const float*)d_in[0];
    const float* k  = (const float*)d_in[1];
    const float* v  = (const float*)d_in[2];
    const float* kc = (const float*)d_in[3];
    const float* vc = (const float*)d_in[4];
    // d_in[5] = slot_mapping (derivable; caches are not outputs)
    const int* btab    = (const int*)d_in[6];
    const int* ctxlens = (const int*)d_in[7];
    float* outp = (float*)d_out;
    float* ws   = (float*)d_ws;   // 32768 partials x 136 floats = 17.8 MB

    gen_kernel  <<<dim3(1024), dim3(256), 0, stream>>>(q, k, v, kc, vc, btab, ctxlens, ws);
    merge_kernel<<<dim3(256),  dim3(256), 0, stream>>>(ws, outp);
    fill_kernel <<<dim3(256),  dim3(512), 0, stream>>>(q, k, v, outp);
}

// Round 18
// 164.843 us; speedup vs baseline: 1.4679x; 1.4679x over previous
//
#include <hip/hip_runtime.h>
#include <hip/hip_bf16.h>

#define HH 32
#define DD 128
#define HD (HH*DD)          // 4096
#define NFILL 2048
#define FLEN 512
#define SCALE_F 0.08838834764831845f
#define NEGINF (-1e30f)
#define PSTRIDE 136         // floats per partial record: [m, l, pad..., acc[128]]

typedef short bf16x8 __attribute__((ext_vector_type(8)));
typedef float f32x4 __attribute__((ext_vector_type(4)));

__device__ __forceinline__ short f2bf(float x) {
    union { float f; unsigned u; } c; c.f = x;
    unsigned u = c.u;
    u += 0x7FFFu + ((u >> 16) & 1u);   // RNE
    return (short)(u >> 16);
}

__device__ __forceinline__ bf16x8 load8_bf16(const float* __restrict__ p) {
    float4 a = *(const float4*)p;
    float4 b = *(const float4*)(p + 4);
    bf16x8 r;
    r[0]=f2bf(a.x); r[1]=f2bf(a.y); r[2]=f2bf(a.z); r[3]=f2bf(a.w);
    r[4]=f2bf(b.x); r[5]=f2bf(b.y); r[6]=f2bf(b.z); r[7]=f2bf(b.w);
    return r;
}

// ======================= GEN (r15 best config: NT loads, half-context blocks) =======================
// 1024 blocks x 256 thr: g=bid>>6, h=(bid>>1)&31, half=bid&1.
// 4 waves x 128 positions; 16-lane group per position, 4 pos/group-iter.
__global__ __launch_bounds__(256)
void gen_kernel(const float* __restrict__ q, const float* __restrict__ k,
                const float* __restrict__ v, const float* __restrict__ kc,
                const float* __restrict__ vc, const int* __restrict__ btab,
                const int* __restrict__ ctxlens, float* __restrict__ ws)
{
    __shared__ int sblk[64];
    __shared__ float accs[16][DD];
    __shared__ float marr[16], larr[16];

    const int bid  = blockIdx.x;
    const int g    = bid >> 6;
    const int h    = (bid >> 1) & 31;
    const int half = bid & 1;
    const int wv   = threadIdx.x >> 6;
    const int lane = threadIdx.x & 63;
    const int g16  = lane >> 4;
    const int li   = lane & 15;
    const int ctx  = ctxlens[g];

    if (threadIdx.x < 64) sblk[threadIdx.x] = btab[g * 64 + threadIdx.x];
    __syncthreads();

    const long qoff = (long)(NFILL + g) * HD + h * DD;
    float qr[8];
    {
        float4 a  = *(const float4*)(q + qoff + li * 8);
        float4 b2 = *(const float4*)(q + qoff + li * 8 + 4);
        qr[0]=a.x; qr[1]=a.y; qr[2]=a.z; qr[3]=a.w;
        qr[4]=b2.x; qr[5]=b2.y; qr[6]=b2.z; qr[7]=b2.w;
    }

    float m = NEGINF, l = 0.f;
    float o[8];
    #pragma unroll
    for (int j = 0; j < 8; ++j) o[j] = 0.f;

    const int wbase = half * 512 + wv * 128;

    #pragma unroll 1
    for (int c = 0; c < 8; ++c) {
        const int pb = wbase + c * 16 + g16 * 4;
        f32x4 ka[4][2], va[4][2];
        #pragma unroll
        for (int i = 0; i < 4; ++i) {
            const int p = pb + i;
            const float* kb; const float* vb;
            if (p == ctx - 1) {            // fresh token lives in k/v, not cache
                kb = k + qoff; vb = v + qoff;
            } else {
                const int slot = sblk[p >> 4] * 16 + (p & 15);
                kb = kc + (long)slot * HD + h * DD;
                vb = vc + (long)slot * HD + h * DD;
            }
            ka[i][0] = __builtin_nontemporal_load((const f32x4*)(kb + li * 8));
            ka[i][1] = __builtin_nontemporal_load((const f32x4*)(kb + li * 8 + 4));
            va[i][0] = __builtin_nontemporal_load((const f32x4*)(vb + li * 8));
            va[i][1] = __builtin_nontemporal_load((const f32x4*)(vb + li * 8 + 4));
        }
        float s[4];
        #pragma unroll
        for (int i = 0; i < 4; ++i) {
            float d0 = ka[i][0][0]*qr[0] + ka[i][0][1]*qr[1] + ka[i][0][2]*qr[2] + ka[i][0][3]*qr[3]
                     + ka[i][1][0]*qr[4] + ka[i][1][1]*qr[5] + ka[i][1][2]*qr[6] + ka[i][1][3]*qr[7];
            d0 += __shfl_xor(d0, 1);
            d0 += __shfl_xor(d0, 2);
            d0 += __shfl_xor(d0, 4);
            d0 += __shfl_xor(d0, 8);
            s[i] = d0 * SCALE_F;
        }
        const float mn = fmaxf(m, fmaxf(fmaxf(s[0], s[1]), fmaxf(s[2], s[3])));
        const float sc = __expf(m - mn);
        const float p0 = __expf(s[0] - mn);
        const float p1 = __expf(s[1] - mn);
        const float p2 = __expf(s[2] - mn);
        const float p3 = __expf(s[3] - mn);
        l = l * sc + (p0 + p1 + p2 + p3);
        #pragma unroll
        for (int j = 0; j < 4; ++j) {
            o[j] = o[j]*sc + p0*va[0][0][j] + p1*va[1][0][j]
                           + p2*va[2][0][j] + p3*va[3][0][j];
            o[j+4] = o[j+4]*sc + p0*va[0][1][j] + p1*va[1][1][j]
                               + p2*va[2][1][j] + p3*va[3][1][j];
        }
        m = mn;
    }

    const int pid = wv * 4 + g16;
    #pragma unroll
    for (int j = 0; j < 8; ++j) accs[pid][li * 8 + j] = o[j];
    if (li == 0) { marr[pid] = m; larr[pid] = l; }
    __syncthreads();

    if (threadIdx.x < DD) {
        const int d = threadIdx.x;
        float M = NEGINF;
        #pragma unroll
        for (int t = 0; t < 16; ++t) M = fmaxf(M, marr[t]);
        float L = 0.f, a = 0.f;
        #pragma unroll
        for (int t = 0; t < 16; ++t) {
            const float cc = __expf(marr[t] - M);
            L += cc * larr[t];
            a += cc * accs[t][d];
        }
        const long base = (long)(((g * 32 + h) * 2) + half) * PSTRIDE;
        ws[base + 8 + d] = a;
        if (d == 0) { ws[base] = M; ws[base + 1] = L; }
    }
}

// ======================= MERGE (r15, unchanged) =======================
__global__ __launch_bounds__(256)
void merge_kernel(const float* __restrict__ ws, float* __restrict__ out)
{
    const int idx = blockIdx.x * 256 + threadIdx.x;
    const int gh  = idx >> 7;
    const int d   = idx & 127;
    const int g   = gh >> 5;
    const int h   = gh & 31;
    const long b0 = (long)gh * 2 * PSTRIDE;
    const long b1 = b0 + PSTRIDE;
    const float m0 = ws[b0], l0 = ws[b0 + 1];
    const float m1 = ws[b1], l1 = ws[b1 + 1];
    const float M  = fmaxf(m0, m1);
    const float e0 = __expf(m0 - M), e1 = __expf(m1 - M);
    const float num = e0 * ws[b0 + 8 + d] + e1 * ws[b1 + 8 + d];
    const float den = e0 * l0 + e1 * l1;
    out[(long)(NFILL + g) * 4096 + h * DD + d] = num / den;
}

// ======================= FILL v5: anti-diagonal q-tile pairing =======================
// 256 blocks x 512 thr: b=bid>>6, h=(bid>>1)&31, jh=bid&1.
// Wave wv owns qtA=2wv+jh (0..15) and qtB=31-qtA (16..31): per-wave tile-computes
// = (qtA/2+1)+((31-qtA)/2+1) = 17 for EVERY wave (was 2wv+10, crit path 24).
__global__ void __launch_bounds__(512, 2) fill_kernel(const float*, const float*, const float*, float*);

struct QS {
    bf16x8 qf[4];
    float  mrow[4], lsum[4];
    f32x4  o[8];
};

__device__ __forceinline__ void qs_init(QS& S, const float* qbase, int g16) {
    #pragma unroll
    for (int c = 0; c < 4; ++c) S.qf[c] = load8_bf16(qbase + c * 32 + g16 * 8);
    #pragma unroll
    for (int r = 0; r < 4; ++r) { S.mrow[r] = NEGINF; S.lsum[r] = 0.f; }
    #pragma unroll
    for (int n = 0; n < 8; ++n) { S.o[n][0]=0.f; S.o[n][1]=0.f; S.o[n][2]=0.f; S.o[n][3]=0.f; }
}

__device__ __forceinline__ void qs_tile(QS& S, int qt, int k0,
                                        const char* Kl, const char* Vt2,
                                        char* pbase, int g16, int li) {
    f32x4 sA; sA[0]=0.f; sA[1]=0.f; sA[2]=0.f; sA[3]=0.f;
    f32x4 sB; sB[0]=0.f; sB[1]=0.f; sB[2]=0.f; sB[3]=0.f;
    #pragma unroll
    for (int c = 0; c < 4; ++c) {
        const int rA = li, rB = li + 16;
        bf16x8 kfA = *(const bf16x8*)(Kl + ((rA * 256 + c * 64 + g16 * 16) ^ ((rA & 7) << 4)));
        bf16x8 kfB = *(const bf16x8*)(Kl + ((rB * 256 + c * 64 + g16 * 16) ^ ((rB & 7) << 4)));
        sA = __builtin_amdgcn_mfma_f32_16x16x32_bf16(S.qf[c], kfA, sA, 0, 0, 0);
        sB = __builtin_amdgcn_mfma_f32_16x16x32_bf16(S.qf[c], kfB, sB, 0, 0, 0);
    }
    float pA[4], pB[4], corr[4];
    #pragma unroll
    for (int r = 0; r < 4; ++r) {
        const int qrow = qt * 16 + g16 * 4 + r;
        float a  = (k0 + li      <= qrow) ? sA[r] * SCALE_F : NEGINF;
        float bb = (k0 + 16 + li <= qrow) ? sB[r] * SCALE_F : NEGINF;
        float rm = fmaxf(a, bb);
        #pragma unroll
        for (int off = 1; off < 16; off <<= 1) rm = fmaxf(rm, __shfl_xor(rm, off));
        const float mn = fmaxf(S.mrow[r], rm);
        corr[r] = __expf(S.mrow[r] - mn);
        pA[r] = __expf(a  - mn);
        pB[r] = __expf(bb - mn);
        float rs = pA[r] + pB[r];
        #pragma unroll
        for (int off = 1; off < 16; off <<= 1) rs += __shfl_xor(rs, off);
        S.lsum[r] = S.lsum[r] * corr[r] + rs;
        S.mrow[r] = mn;
    }
    #pragma unroll
    for (int n = 0; n < 8; ++n)
        #pragma unroll
        for (int r = 0; r < 4; ++r) S.o[n][r] *= corr[r];

    #pragma unroll
    for (int r = 0; r < 4; ++r) {
        const int row = g16 * 4 + r;
        const int xo  = (row & 3) << 4;
        *(short*)(pbase + ((row * 64 + li * 2     ) ^ xo)) = f2bf(pA[r]);
        *(short*)(pbase + ((row * 64 + 32 + li * 2) ^ xo)) = f2bf(pB[r]);
    }
    asm volatile("s_waitcnt lgkmcnt(0)" ::: "memory");
    __builtin_amdgcn_sched_barrier(0);
    bf16x8 pa = *(const bf16x8*)(pbase + ((li * 64 + g16 * 16) ^ ((li & 3) << 4)));

    #pragma unroll
    for (int n = 0; n < 8; ++n) {
        bf16x8 vf = *(const bf16x8*)(Vt2 + (n * 1024 + g16 * 256 + li * 16));
        S.o[n] = __builtin_amdgcn_mfma_f32_16x16x32_bf16(pa, vf, S.o[n], 0, 0, 0);
    }
}

__device__ __forceinline__ void qs_out(QS& S, int qt, int b, int h, int g16, int li,
                                       float* __restrict__ out) {
    float inv[4];
    #pragma unroll
    for (int r = 0; r < 4; ++r) inv[r] = 1.f / S.lsum[r];
    #pragma unroll
    for (int n = 0; n < 8; ++n) {
        #pragma unroll
        for (int r = 0; r < 4; ++r) {
            const int t = b * FLEN + qt * 16 + g16 * 4 + r;
            out[(long)t * 4096 + h * DD + n * 16 + li] = S.o[n][r] * inv[r];
        }
    }
}

__global__ void __launch_bounds__(512, 2)
fill_kernel(const float* __restrict__ q, const float* __restrict__ k,
            const float* __restrict__ v, float* __restrict__ out)
{
    __shared__ short Kl[32 * 128];
    __shared__ short Vt2[8 * 4 * 16 * 8];
    __shared__ short plds[8][16][32];

    const int bid = blockIdx.x;
    const int b   = bid >> 6;
    const int h   = (bid >> 1) & 31;
    const int jh  = bid & 1;
    const int tid  = threadIdx.x;
    const int wv   = tid >> 6;
    const int lane = tid & 63;
    const int g16  = lane >> 4;
    const int li   = lane & 15;

    const int qtA = 2 * wv + jh;       // 0..15
    const int qtB = 31 - qtA;          // 16..31 (anti-diagonal: per-wave work = 17)
    const int npA = qtA / 2 + 1;
    const int npB = qtB / 2 + 1;

    QS SA, SB2;
    qs_init(SA,  q + ((long)(b * FLEN + qtA * 16 + li) * HH + h) * DD, g16);
    qs_init(SB2, q + ((long)(b * FLEN + qtB * 16 + li) * HH + h) * DD, g16);

    const int spos = tid >> 4;
    const int sd8  = tid & 15;
    const int vd   = tid & 127;
    const int voct = tid >> 7;

    char* pbase = (char*)&plds[wv][0][0];

    for (int kp = 0; kp < 16; ++kp) {
        const int k0 = kp * 32;
        {
            const float* src = k + ((long)(b * FLEN + k0 + spos) * HH + h) * DD + sd8 * 8;
            bf16x8 w = load8_bf16(src);
            const int base = spos * 256 + sd8 * 16;
            *(bf16x8*)((char*)Kl + (base ^ ((spos & 7) << 4))) = w;
        }
        {
            const float* src = v + ((long)(b * FLEN + k0 + voct * 8) * HH + h) * DD + vd;
            bf16x8 w;
            #pragma unroll
            for (int jj = 0; jj < 8; ++jj)
                w[jj] = f2bf(src[(long)jj * HD]);
            *(bf16x8*)((char*)Vt2 + ((vd >> 4) * 1024 + voct * 256 + (vd & 15) * 16)) = w;
        }
        __syncthreads();

        if (kp < npA) qs_tile(SA,  qtA, k0, (const char*)Kl, (const char*)Vt2, pbase, g16, li);
        if (kp < npB) qs_tile(SB2, qtB, k0, (const char*)Kl, (const char*)Vt2, pbase, g16, li);

        __syncthreads();
    }

    qs_out(SA,  qtA, b, h, g16, li, out);
    qs_out(SB2, qtB, b, h, g16, li, out);
}

extern "C" void kernel_launch(void* const* d_in, const int* in_sizes, int n_in,
                              void* d_out, int out_size, void* d_ws, size_t ws_size,
                              hipStream_t stream) {
    const float* q  = (const float*)d_in[0];
    const float* k  = (const float*)d_in[1];
    const float* v  = (const float*)d_in[2];
    const float* kc = (const float*)d_in[3];
    const float* vc = (const float*)d_in[4];
    // d_in[5] = slot_mapping (derivable; caches are not outputs)
    const int* btab    = (const int*)d_in[6];
    const int* ctxlens = (const int*)d_in[7];
    float* outp = (float*)d_out;
    float* ws   = (float*)d_ws;   // 1024 partials x 136 floats = 557 KB

    gen_kernel  <<<dim3(1024), dim3(256), 0, stream>>>(q, k, v, kc, vc, btab, ctxlens, ws);
    merge_kernel<<<dim3(256),  dim3(256), 0, stream>>>(ws, outp);
    fill_kernel <<<dim3(256),  dim3(512), 0, stream>>>(q, k, v, outp);
}

// Round 19
// 153.049 us; speedup vs baseline: 1.5811x; 1.0771x over previous
//
#include <hip/hip_runtime.h>
#include <hip/hip_bf16.h>

#define HH 32
#define DD 128
#define HD (HH*DD)          // 4096
#define NFILL 2048
#define FLEN 512
#define SCALE_F 0.08838834764831845f
#define NEGINF (-1e30f)
#define PSTRIDE 136         // floats per partial record: [m, l, pad..., acc[128]]

typedef short bf16x8 __attribute__((ext_vector_type(8)));
typedef float f32x4 __attribute__((ext_vector_type(4)));

__device__ __forceinline__ short f2bf(float x) {
    union { float f; unsigned u; } c; c.f = x;
    unsigned u = c.u;
    u += 0x7FFFu + ((u >> 16) & 1u);   // RNE
    return (short)(u >> 16);
}

__device__ __forceinline__ bf16x8 load8_bf16(const float* __restrict__ p) {
    float4 a = *(const float4*)p;
    float4 b = *(const float4*)(p + 4);
    bf16x8 r;
    r[0]=f2bf(a.x); r[1]=f2bf(a.y); r[2]=f2bf(a.z); r[3]=f2bf(a.w);
    r[4]=f2bf(b.x); r[5]=f2bf(b.y); r[6]=f2bf(b.z); r[7]=f2bf(b.w);
    return r;
}

// ======================= GEN (r15 best config: NT loads, half-context blocks) =======================
__global__ __launch_bounds__(256)
void gen_kernel(const float* __restrict__ q, const float* __restrict__ k,
                const float* __restrict__ v, const float* __restrict__ kc,
                const float* __restrict__ vc, const int* __restrict__ btab,
                const int* __restrict__ ctxlens, float* __restrict__ ws)
{
    __shared__ int sblk[64];
    __shared__ float accs[16][DD];
    __shared__ float marr[16], larr[16];

    const int bid  = blockIdx.x;
    const int g    = bid >> 6;
    const int h    = (bid >> 1) & 31;
    const int half = bid & 1;
    const int wv   = threadIdx.x >> 6;
    const int lane = threadIdx.x & 63;
    const int g16  = lane >> 4;
    const int li   = lane & 15;
    const int ctx  = ctxlens[g];

    if (threadIdx.x < 64) sblk[threadIdx.x] = btab[g * 64 + threadIdx.x];
    __syncthreads();

    const long qoff = (long)(NFILL + g) * HD + h * DD;
    float qr[8];
    {
        float4 a  = *(const float4*)(q + qoff + li * 8);
        float4 b2 = *(const float4*)(q + qoff + li * 8 + 4);
        qr[0]=a.x; qr[1]=a.y; qr[2]=a.z; qr[3]=a.w;
        qr[4]=b2.x; qr[5]=b2.y; qr[6]=b2.z; qr[7]=b2.w;
    }

    float m = NEGINF, l = 0.f;
    float o[8];
    #pragma unroll
    for (int j = 0; j < 8; ++j) o[j] = 0.f;

    const int wbase = half * 512 + wv * 128;

    #pragma unroll 1
    for (int c = 0; c < 8; ++c) {
        const int pb = wbase + c * 16 + g16 * 4;
        f32x4 ka[4][2], va[4][2];
        #pragma unroll
        for (int i = 0; i < 4; ++i) {
            const int p = pb + i;
            const float* kb; const float* vb;
            if (p == ctx - 1) {            // fresh token lives in k/v, not cache
                kb = k + qoff; vb = v + qoff;
            } else {
                const int slot = sblk[p >> 4] * 16 + (p & 15);
                kb = kc + (long)slot * HD + h * DD;
                vb = vc + (long)slot * HD + h * DD;
            }
            ka[i][0] = __builtin_nontemporal_load((const f32x4*)(kb + li * 8));
            ka[i][1] = __builtin_nontemporal_load((const f32x4*)(kb + li * 8 + 4));
            va[i][0] = __builtin_nontemporal_load((const f32x4*)(vb + li * 8));
            va[i][1] = __builtin_nontemporal_load((const f32x4*)(vb + li * 8 + 4));
        }
        float s[4];
        #pragma unroll
        for (int i = 0; i < 4; ++i) {
            float d0 = ka[i][0][0]*qr[0] + ka[i][0][1]*qr[1] + ka[i][0][2]*qr[2] + ka[i][0][3]*qr[3]
                     + ka[i][1][0]*qr[4] + ka[i][1][1]*qr[5] + ka[i][1][2]*qr[6] + ka[i][1][3]*qr[7];
            d0 += __shfl_xor(d0, 1);
            d0 += __shfl_xor(d0, 2);
            d0 += __shfl_xor(d0, 4);
            d0 += __shfl_xor(d0, 8);
            s[i] = d0 * SCALE_F;
        }
        const float mn = fmaxf(m, fmaxf(fmaxf(s[0], s[1]), fmaxf(s[2], s[3])));
        const float sc = __expf(m - mn);
        const float p0 = __expf(s[0] - mn);
        const float p1 = __expf(s[1] - mn);
        const float p2 = __expf(s[2] - mn);
        const float p3 = __expf(s[3] - mn);
        l = l * sc + (p0 + p1 + p2 + p3);
        #pragma unroll
        for (int j = 0; j < 4; ++j) {
            o[j] = o[j]*sc + p0*va[0][0][j] + p1*va[1][0][j]
                           + p2*va[2][0][j] + p3*va[3][0][j];
            o[j+4] = o[j+4]*sc + p0*va[0][1][j] + p1*va[1][1][j]
                               + p2*va[2][1][j] + p3*va[3][1][j];
        }
        m = mn;
    }

    const int pid = wv * 4 + g16;
    #pragma unroll
    for (int j = 0; j < 8; ++j) accs[pid][li * 8 + j] = o[j];
    if (li == 0) { marr[pid] = m; larr[pid] = l; }
    __syncthreads();

    if (threadIdx.x < DD) {
        const int d = threadIdx.x;
        float M = NEGINF;
        #pragma unroll
        for (int t = 0; t < 16; ++t) M = fmaxf(M, marr[t]);
        float L = 0.f, a = 0.f;
        #pragma unroll
        for (int t = 0; t < 16; ++t) {
            const float cc = __expf(marr[t] - M);
            L += cc * larr[t];
            a += cc * accs[t][d];
        }
        const long base = (long)(((g * 32 + h) * 2) + half) * PSTRIDE;
        ws[base + 8 + d] = a;
        if (d == 0) { ws[base] = M; ws[base + 1] = L; }
    }
}

// ======================= MERGE (unchanged) =======================
__global__ __launch_bounds__(256)
void merge_kernel(const float* __restrict__ ws, float* __restrict__ out)
{
    const int idx = blockIdx.x * 256 + threadIdx.x;
    const int gh  = idx >> 7;
    const int d   = idx & 127;
    const int g   = gh >> 5;
    const int h   = gh & 31;
    const long b0 = (long)gh * 2 * PSTRIDE;
    const long b1 = b0 + PSTRIDE;
    const float m0 = ws[b0], l0 = ws[b0 + 1];
    const float m1 = ws[b1], l1 = ws[b1 + 1];
    const float M  = fmaxf(m0, m1);
    const float e0 = __expf(m0 - M), e1 = __expf(m1 - M);
    const float num = e0 * ws[b0 + 8 + d] + e1 * ws[b1 + 8 + d];
    const float den = e0 * l0 + e1 * l1;
    out[(long)(NFILL + g) * 4096 + h * DD + d] = num / den;
}

// ======================= FILL v6: BK=64 (8 trips), anti-diagonal pairing =======================
// 256 blocks x 512 thr: b=bid>>6, h=(bid>>1)&31, jh=bid&1.
// Wave wv owns qtA=2wv+jh, qtB=31-qtA (equal 17 tile-computes/wave).
// 64 positions staged per trip -> 8 trips, half the barriers/stage-latency events.
struct QS {
    bf16x8 qf[4];
    float  mrow[4], lsum[4];
    f32x4  o[8];
};

__device__ __forceinline__ void qs_init(QS& S, const float* qbase, int g16) {
    #pragma unroll
    for (int c = 0; c < 4; ++c) S.qf[c] = load8_bf16(qbase + c * 32 + g16 * 8);
    #pragma unroll
    for (int r = 0; r < 4; ++r) { S.mrow[r] = NEGINF; S.lsum[r] = 0.f; }
    #pragma unroll
    for (int n = 0; n < 8; ++n) { S.o[n][0]=0.f; S.o[n][1]=0.f; S.o[n][2]=0.f; S.o[n][3]=0.f; }
}

// sub = which 32-pos half of the 64-pos buffer; k0 = absolute key base (multiple of 32)
__device__ __forceinline__ void qs_tile(QS& S, int qt, int k0, int sub,
                                        const char* Kl, const char* Vt2,
                                        char* pbase, int g16, int li) {
    f32x4 sA; sA[0]=0.f; sA[1]=0.f; sA[2]=0.f; sA[3]=0.f;
    f32x4 sB; sB[0]=0.f; sB[1]=0.f; sB[2]=0.f; sB[3]=0.f;
    const int r0 = sub * 32;
    #pragma unroll
    for (int c = 0; c < 4; ++c) {
        const int rA = r0 + li, rB = r0 + li + 16;
        bf16x8 kfA = *(const bf16x8*)(Kl + ((rA * 256 + c * 64 + g16 * 16) ^ ((rA & 7) << 4)));
        bf16x8 kfB = *(const bf16x8*)(Kl + ((rB * 256 + c * 64 + g16 * 16) ^ ((rB & 7) << 4)));
        sA = __builtin_amdgcn_mfma_f32_16x16x32_bf16(S.qf[c], kfA, sA, 0, 0, 0);
        sB = __builtin_amdgcn_mfma_f32_16x16x32_bf16(S.qf[c], kfB, sB, 0, 0, 0);
    }
    float pA[4], pB[4], corr[4];
    #pragma unroll
    for (int r = 0; r < 4; ++r) {
        const int qrow = qt * 16 + g16 * 4 + r;
        float a  = (k0 + li      <= qrow) ? sA[r] * SCALE_F : NEGINF;
        float bb = (k0 + 16 + li <= qrow) ? sB[r] * SCALE_F : NEGINF;
        float rm = fmaxf(a, bb);
        #pragma unroll
        for (int off = 1; off < 16; off <<= 1) rm = fmaxf(rm, __shfl_xor(rm, off));
        const float mn = fmaxf(S.mrow[r], rm);
        corr[r] = __expf(S.mrow[r] - mn);
        pA[r] = __expf(a  - mn);
        pB[r] = __expf(bb - mn);
        float rs = pA[r] + pB[r];
        #pragma unroll
        for (int off = 1; off < 16; off <<= 1) rs += __shfl_xor(rs, off);
        S.lsum[r] = S.lsum[r] * corr[r] + rs;
        S.mrow[r] = mn;
    }
    #pragma unroll
    for (int n = 0; n < 8; ++n)
        #pragma unroll
        for (int r = 0; r < 4; ++r) S.o[n][r] *= corr[r];

    #pragma unroll
    for (int r = 0; r < 4; ++r) {
        const int row = g16 * 4 + r;
        const int xo  = (row & 3) << 4;
        *(short*)(pbase + ((row * 64 + li * 2     ) ^ xo)) = f2bf(pA[r]);
        *(short*)(pbase + ((row * 64 + 32 + li * 2) ^ xo)) = f2bf(pB[r]);
    }
    asm volatile("s_waitcnt lgkmcnt(0)" ::: "memory");
    __builtin_amdgcn_sched_barrier(0);
    bf16x8 pa = *(const bf16x8*)(pbase + ((li * 64 + g16 * 16) ^ ((li & 3) << 4)));

    const int obase = (sub * 4 + g16) * 256 + li * 16;
    #pragma unroll
    for (int n = 0; n < 8; ++n) {
        bf16x8 vf = *(const bf16x8*)(Vt2 + (n * 2048 + obase));
        S.o[n] = __builtin_amdgcn_mfma_f32_16x16x32_bf16(pa, vf, S.o[n], 0, 0, 0);
    }
}

__device__ __forceinline__ void qs_out(QS& S, int qt, int b, int h, int g16, int li,
                                       float* __restrict__ out) {
    float inv[4];
    #pragma unroll
    for (int r = 0; r < 4; ++r) inv[r] = 1.f / S.lsum[r];
    #pragma unroll
    for (int n = 0; n < 8; ++n) {
        #pragma unroll
        for (int r = 0; r < 4; ++r) {
            const int t = b * FLEN + qt * 16 + g16 * 4 + r;
            out[(long)t * 4096 + h * DD + n * 16 + li] = S.o[n][r] * inv[r];
        }
    }
}

__global__ void __launch_bounds__(512, 2)
fill_kernel(const float* __restrict__ q, const float* __restrict__ k,
            const float* __restrict__ v, float* __restrict__ out)
{
    __shared__ short Kl[64 * 128];          // 16 KB, [row][d] bf16, XOR-swizzled
    __shared__ short Vt2[8 * 8 * 16 * 8];   // 16 KB, [n][oct 0..7][li][j] fragment-shaped
    __shared__ short plds[8][16][32];       // 8 KB per-wave P tiles

    const int bid = blockIdx.x;
    const int b   = bid >> 6;
    const int h   = (bid >> 1) & 31;
    const int jh  = bid & 1;
    const int tid  = threadIdx.x;
    const int wv   = tid >> 6;
    const int lane = tid & 63;
    const int g16  = lane >> 4;
    const int li   = lane & 15;

    const int qtA = 2 * wv + jh;       // 0..15
    const int qtB = 31 - qtA;          // 16..31
    const int npA = qtA / 2 + 1;       // 32-pos k-tiles needed
    const int npB = qtB / 2 + 1;

    QS SA, SB2;
    qs_init(SA,  q + ((long)(b * FLEN + qtA * 16 + li) * HH + h) * DD, g16);
    qs_init(SB2, q + ((long)(b * FLEN + qtB * 16 + li) * HH + h) * DD, g16);

    const int spos = tid >> 4;    // K staging: row base 0..31 (handles +32 too)
    const int sd8  = tid & 15;    //            8-float chunk
    const int vd   = tid & 127;   // V staging: d
    const int voct = tid >> 7;    //            oct base 0..3 (handles +4 too)

    char* pbase = (char*)&plds[wv][0][0];

    for (int kp = 0; kp < 8; ++kp) {
        const int k0 = kp * 64;
        // ---- stage K: 2 rows/thread, one b128 write each (uniform banks) ----
        #pragma unroll
        for (int rr = 0; rr < 2; ++rr) {
            const int row = spos + rr * 32;
            const float* src = k + ((long)(b * FLEN + k0 + row) * HH + h) * DD + sd8 * 8;
            bf16x8 w = load8_bf16(src);
            const int base = row * 256 + sd8 * 16;
            *(bf16x8*)((char*)Kl + (base ^ ((row & 7) << 4))) = w;
        }
        // ---- stage V fragment-shaped: 2 octs/thread ----
        #pragma unroll
        for (int oo = 0; oo < 2; ++oo) {
            const int oct = voct + oo * 4;
            const float* src = v + ((long)(b * FLEN + k0 + oct * 8) * HH + h) * DD + vd;
            bf16x8 w;
            #pragma unroll
            for (int jj = 0; jj < 8; ++jj)
                w[jj] = f2bf(src[(long)jj * HD]);
            *(bf16x8*)((char*)Vt2 + ((vd >> 4) * 2048 + oct * 256 + (vd & 15) * 16)) = w;
        }
        __syncthreads();

        const int kt0 = 2 * kp, kt1 = 2 * kp + 1;
        if (kt0 < npA) qs_tile(SA,  qtA, kt0 * 32, 0, (const char*)Kl, (const char*)Vt2, pbase, g16, li);
        if (kt1 < npA) qs_tile(SA,  qtA, kt1 * 32, 1, (const char*)Kl, (const char*)Vt2, pbase, g16, li);
        if (kt0 < npB) qs_tile(SB2, qtB, kt0 * 32, 0, (const char*)Kl, (const char*)Vt2, pbase, g16, li);
        if (kt1 < npB) qs_tile(SB2, qtB, kt1 * 32, 1, (const char*)Kl, (const char*)Vt2, pbase, g16, li);

        __syncthreads();
    }

    qs_out(SA,  qtA, b, h, g16, li, out);
    qs_out(SB2, qtB, b, h, g16, li, out);
}

extern "C" void kernel_launch(void* const* d_in, const int* in_sizes, int n_in,
                              void* d_out, int out_size, void* d_ws, size_t ws_size,
                              hipStream_t stream) {
    const float* q  = (const float*)d_in[0];
    const float* k  = (const float*)d_in[1];
    const float* v  = (const float*)d_in[2];
    const float* kc = (const float*)d_in[3];
    const float* vc = (const float*)d_in[4];
    // d_in[5] = slot_mapping (derivable; caches are not outputs)
    const int* btab    = (const int*)d_in[6];
    const int* ctxlens = (const int*)d_in[7];
    float* outp = (float*)d_out;
    float* ws   = (float*)d_ws;   // 1024 partials x 136 floats = 557 KB

    gen_kernel  <<<dim3(1024), dim3(256), 0, stream>>>(q, k, v, kc, vc, btab, ctxlens, ws);
    merge_kernel<<<dim3(256),  dim3(256), 0, stream>>>(ws, outp);
    fill_kernel <<<dim3(256),  dim3(512), 0, stream>>>(q, k, v, outp);
}

// Round 20
// 149.774 us; speedup vs baseline: 1.6156x; 1.0219x over previous
//
#include <hip/hip_runtime.h>
#include <hip/hip_bf16.h>

#define HH 32
#define DD 128
#define HD (HH*DD)          // 4096
#define NFILL 2048
#define FLEN 512
#define SCALE_F 0.08838834764831845f
#define NEGINF (-1e30f)
#define PSTRIDE 136         // floats per partial record: [m, l, pad..., acc[128]]

typedef short bf16x8 __attribute__((ext_vector_type(8)));
typedef float f32x4 __attribute__((ext_vector_type(4)));

__device__ __forceinline__ short f2bf(float x) {
    union { float f; unsigned u; } c; c.f = x;
    unsigned u = c.u;
    u += 0x7FFFu + ((u >> 16) & 1u);   // RNE
    return (short)(u >> 16);
}

__device__ __forceinline__ bf16x8 load8_bf16(const float* __restrict__ p) {
    float4 a = *(const float4*)p;
    float4 b = *(const float4*)(p + 4);
    bf16x8 r;
    r[0]=f2bf(a.x); r[1]=f2bf(a.y); r[2]=f2bf(a.z); r[3]=f2bf(a.w);
    r[4]=f2bf(b.x); r[5]=f2bf(b.y); r[6]=f2bf(b.z); r[7]=f2bf(b.w);
    return r;
}

// ======================= GEN (r15 best config: NT loads, half-context blocks) =======================
__global__ __launch_bounds__(256)
void gen_kernel(const float* __restrict__ q, const float* __restrict__ k,
                const float* __restrict__ v, const float* __restrict__ kc,
                const float* __restrict__ vc, const int* __restrict__ btab,
                const int* __restrict__ ctxlens, float* __restrict__ ws)
{
    __shared__ int sblk[64];
    __shared__ float accs[16][DD];
    __shared__ float marr[16], larr[16];

    const int bid  = blockIdx.x;
    const int g    = bid >> 6;
    const int h    = (bid >> 1) & 31;
    const int half = bid & 1;
    const int wv   = threadIdx.x >> 6;
    const int lane = threadIdx.x & 63;
    const int g16  = lane >> 4;
    const int li   = lane & 15;
    const int ctx  = ctxlens[g];

    if (threadIdx.x < 64) sblk[threadIdx.x] = btab[g * 64 + threadIdx.x];
    __syncthreads();

    const long qoff = (long)(NFILL + g) * HD + h * DD;
    float qr[8];
    {
        float4 a  = *(const float4*)(q + qoff + li * 8);
        float4 b2 = *(const float4*)(q + qoff + li * 8 + 4);
        qr[0]=a.x; qr[1]=a.y; qr[2]=a.z; qr[3]=a.w;
        qr[4]=b2.x; qr[5]=b2.y; qr[6]=b2.z; qr[7]=b2.w;
    }

    float m = NEGINF, l = 0.f;
    float o[8];
    #pragma unroll
    for (int j = 0; j < 8; ++j) o[j] = 0.f;

    const int wbase = half * 512 + wv * 128;

    #pragma unroll 1
    for (int c = 0; c < 8; ++c) {
        const int pb = wbase + c * 16 + g16 * 4;
        f32x4 ka[4][2], va[4][2];
        #pragma unroll
        for (int i = 0; i < 4; ++i) {
            const int p = pb + i;
            const float* kb; const float* vb;
            if (p == ctx - 1) {            // fresh token lives in k/v, not cache
                kb = k + qoff; vb = v + qoff;
            } else {
                const int slot = sblk[p >> 4] * 16 + (p & 15);
                kb = kc + (long)slot * HD + h * DD;
                vb = vc + (long)slot * HD + h * DD;
            }
            ka[i][0] = __builtin_nontemporal_load((const f32x4*)(kb + li * 8));
            ka[i][1] = __builtin_nontemporal_load((const f32x4*)(kb + li * 8 + 4));
            va[i][0] = __builtin_nontemporal_load((const f32x4*)(vb + li * 8));
            va[i][1] = __builtin_nontemporal_load((const f32x4*)(vb + li * 8 + 4));
        }
        float s[4];
        #pragma unroll
        for (int i = 0; i < 4; ++i) {
            float d0 = ka[i][0][0]*qr[0] + ka[i][0][1]*qr[1] + ka[i][0][2]*qr[2] + ka[i][0][3]*qr[3]
                     + ka[i][1][0]*qr[4] + ka[i][1][1]*qr[5] + ka[i][1][2]*qr[6] + ka[i][1][3]*qr[7];
            d0 += __shfl_xor(d0, 1);
            d0 += __shfl_xor(d0, 2);
            d0 += __shfl_xor(d0, 4);
            d0 += __shfl_xor(d0, 8);
            s[i] = d0 * SCALE_F;
        }
        const float mn = fmaxf(m, fmaxf(fmaxf(s[0], s[1]), fmaxf(s[2], s[3])));
        const float sc = __expf(m - mn);
        const float p0 = __expf(s[0] - mn);
        const float p1 = __expf(s[1] - mn);
        const float p2 = __expf(s[2] - mn);
        const float p3 = __expf(s[3] - mn);
        l = l * sc + (p0 + p1 + p2 + p3);
        #pragma unroll
        for (int j = 0; j < 4; ++j) {
            o[j] = o[j]*sc + p0*va[0][0][j] + p1*va[1][0][j]
                           + p2*va[2][0][j] + p3*va[3][0][j];
            o[j+4] = o[j+4]*sc + p0*va[0][1][j] + p1*va[1][1][j]
                               + p2*va[2][1][j] + p3*va[3][1][j];
        }
        m = mn;
    }

    const int pid = wv * 4 + g16;
    #pragma unroll
    for (int j = 0; j < 8; ++j) accs[pid][li * 8 + j] = o[j];
    if (li == 0) { marr[pid] = m; larr[pid] = l; }
    __syncthreads();

    if (threadIdx.x < DD) {
        const int d = threadIdx.x;
        float M = NEGINF;
        #pragma unroll
        for (int t = 0; t < 16; ++t) M = fmaxf(M, marr[t]);
        float L = 0.f, a = 0.f;
        #pragma unroll
        for (int t = 0; t < 16; ++t) {
            const float cc = __expf(marr[t] - M);
            L += cc * larr[t];
            a += cc * accs[t][d];
        }
        const long base = (long)(((g * 32 + h) * 2) + half) * PSTRIDE;
        ws[base + 8 + d] = a;
        if (d == 0) { ws[base] = M; ws[base + 1] = L; }
    }
}

// ======================= FILL v7: merge prologue + T14 reg-staged BK=64 =======================
// 256 blocks x 512 thr: b=bid>>6, h=(bid>>1)&31, jh=bid&1. Wave wv: qtA=2wv+jh, qtB=31-qtA.
// Prologue: each block merges 256 (gh,d) gen items (tid<256) — replaces merge kernel.
// Staging: trip kp+1's K/V global loads issued into REGISTERS right after the compute
// barrier (latency hides under ~4 tile-computes); ds_write at top of next trip (T14).
struct QS {
    bf16x8 qf[4];
    float  mrow[4], lsum[4];
    f32x4  o[8];
};

__device__ __forceinline__ void qs_init(QS& S, const float* qbase, int g16) {
    #pragma unroll
    for (int c = 0; c < 4; ++c) S.qf[c] = load8_bf16(qbase + c * 32 + g16 * 8);
    #pragma unroll
    for (int r = 0; r < 4; ++r) { S.mrow[r] = NEGINF; S.lsum[r] = 0.f; }
    #pragma unroll
    for (int n = 0; n < 8; ++n) { S.o[n][0]=0.f; S.o[n][1]=0.f; S.o[n][2]=0.f; S.o[n][3]=0.f; }
}

__device__ __forceinline__ void qs_tile(QS& S, int qt, int k0, int sub,
                                        const char* Kl, const char* Vt2,
                                        char* pbase, int g16, int li) {
    f32x4 sA; sA[0]=0.f; sA[1]=0.f; sA[2]=0.f; sA[3]=0.f;
    f32x4 sB; sB[0]=0.f; sB[1]=0.f; sB[2]=0.f; sB[3]=0.f;
    const int r0 = sub * 32;
    #pragma unroll
    for (int c = 0; c < 4; ++c) {
        const int rA = r0 + li, rB = r0 + li + 16;
        bf16x8 kfA = *(const bf16x8*)(Kl + ((rA * 256 + c * 64 + g16 * 16) ^ ((rA & 7) << 4)));
        bf16x8 kfB = *(const bf16x8*)(Kl + ((rB * 256 + c * 64 + g16 * 16) ^ ((rB & 7) << 4)));
        sA = __builtin_amdgcn_mfma_f32_16x16x32_bf16(S.qf[c], kfA, sA, 0, 0, 0);
        sB = __builtin_amdgcn_mfma_f32_16x16x32_bf16(S.qf[c], kfB, sB, 0, 0, 0);
    }
    float pA[4], pB[4], corr[4];
    #pragma unroll
    for (int r = 0; r < 4; ++r) {
        const int qrow = qt * 16 + g16 * 4 + r;
        float a  = (k0 + li      <= qrow) ? sA[r] * SCALE_F : NEGINF;
        float bb = (k0 + 16 + li <= qrow) ? sB[r] * SCALE_F : NEGINF;
        float rm = fmaxf(a, bb);
        #pragma unroll
        for (int off = 1; off < 16; off <<= 1) rm = fmaxf(rm, __shfl_xor(rm, off));
        const float mn = fmaxf(S.mrow[r], rm);
        corr[r] = __expf(S.mrow[r] - mn);
        pA[r] = __expf(a  - mn);
        pB[r] = __expf(bb - mn);
        float rs = pA[r] + pB[r];
        #pragma unroll
        for (int off = 1; off < 16; off <<= 1) rs += __shfl_xor(rs, off);
        S.lsum[r] = S.lsum[r] * corr[r] + rs;
        S.mrow[r] = mn;
    }
    #pragma unroll
    for (int n = 0; n < 8; ++n)
        #pragma unroll
        for (int r = 0; r < 4; ++r) S.o[n][r] *= corr[r];

    #pragma unroll
    for (int r = 0; r < 4; ++r) {
        const int row = g16 * 4 + r;
        const int xo  = (row & 3) << 4;
        *(short*)(pbase + ((row * 64 + li * 2     ) ^ xo)) = f2bf(pA[r]);
        *(short*)(pbase + ((row * 64 + 32 + li * 2) ^ xo)) = f2bf(pB[r]);
    }
    asm volatile("s_waitcnt lgkmcnt(0)" ::: "memory");
    __builtin_amdgcn_sched_barrier(0);
    bf16x8 pa = *(const bf16x8*)(pbase + ((li * 64 + g16 * 16) ^ ((li & 3) << 4)));

    const int obase = (sub * 4 + g16) * 256 + li * 16;
    #pragma unroll
    for (int n = 0; n < 8; ++n) {
        bf16x8 vf = *(const bf16x8*)(Vt2 + (n * 2048 + obase));
        S.o[n] = __builtin_amdgcn_mfma_f32_16x16x32_bf16(pa, vf, S.o[n], 0, 0, 0);
    }
}

__device__ __forceinline__ void qs_out(QS& S, int qt, int b, int h, int g16, int li,
                                       float* __restrict__ out) {
    float inv[4];
    #pragma unroll
    for (int r = 0; r < 4; ++r) inv[r] = 1.f / S.lsum[r];
    #pragma unroll
    for (int n = 0; n < 8; ++n) {
        #pragma unroll
        for (int r = 0; r < 4; ++r) {
            const int t = b * FLEN + qt * 16 + g16 * 4 + r;
            out[(long)t * 4096 + h * DD + n * 16 + li] = S.o[n][r] * inv[r];
        }
    }
}

__global__ void __launch_bounds__(512, 1)   // grid=256 pins 1 block/CU; no VGPR cap needed
fill_kernel(const float* __restrict__ q, const float* __restrict__ k,
            const float* __restrict__ v, const float* __restrict__ ws,
            float* __restrict__ out)
{
    __shared__ short Kl[64 * 128];          // 16 KB
    __shared__ short Vt2[8 * 8 * 16 * 8];   // 16 KB
    __shared__ short plds[8][16][32];       // 8 KB

    const int bid = blockIdx.x;
    const int b   = bid >> 6;
    const int h   = (bid >> 1) & 31;
    const int jh  = bid & 1;
    const int tid  = threadIdx.x;
    const int wv   = tid >> 6;
    const int lane = tid & 63;
    const int g16  = lane >> 4;
    const int li   = lane & 15;

    // ---- merge prologue: 256 (gh,d) items per block (replaces merge kernel) ----
    if (tid < 256) {
        const int idx = bid * 256 + tid;   // 65536 = 512 gh x 128 d
        const int gh  = idx >> 7;
        const int d   = idx & 127;
        const int g   = gh >> 5;
        const int h2  = gh & 31;
        const long b0 = (long)gh * 2 * PSTRIDE;
        const long b1 = b0 + PSTRIDE;
        const float m0 = ws[b0], l0 = ws[b0 + 1];
        const float m1 = ws[b1], l1 = ws[b1 + 1];
        const float M  = fmaxf(m0, m1);
        const float e0 = __expf(m0 - M), e1 = __expf(m1 - M);
        const float num = e0 * ws[b0 + 8 + d] + e1 * ws[b1 + 8 + d];
        const float den = e0 * l0 + e1 * l1;
        out[(long)(NFILL + g) * 4096 + h2 * DD + d] = num / den;
    }

    const int qtA = 2 * wv + jh;       // 0..15
    const int qtB = 31 - qtA;          // 16..31
    const int npA = qtA / 2 + 1;
    const int npB = qtB / 2 + 1;

    QS SA, SB2;
    qs_init(SA,  q + ((long)(b * FLEN + qtA * 16 + li) * HH + h) * DD, g16);
    qs_init(SB2, q + ((long)(b * FLEN + qtB * 16 + li) * HH + h) * DD, g16);

    const int spos = tid >> 4;    // K staging: rows {spos, spos+32}
    const int sd8  = tid & 15;    //            8-float chunk
    const int vd   = tid & 127;   // V staging: d
    const int voct = tid >> 7;    //            octs {voct, voct+4}

    char* pbase = (char*)&plds[wv][0][0];

    // T14 staging registers (static indices only)
    float4 kr00, kr01, kr10, kr11;     // K rows: [rr][half-of-8-floats]
    float  vr0[8], vr1[8];             // V octs

    #define STAGE_LOAD(KP) do { \
        const float* s0 = k + ((long)(b * FLEN + (KP) * 64 + spos) * HH + h) * DD + sd8 * 8; \
        kr00 = *(const float4*)s0;  kr01 = *(const float4*)(s0 + 4); \
        const float* s1 = s0 + (long)32 * HD; \
        kr10 = *(const float4*)s1;  kr11 = *(const float4*)(s1 + 4); \
        const float* t0 = v + ((long)(b * FLEN + (KP) * 64 + voct * 8) * HH + h) * DD + vd; \
        const float* t1 = t0 + (long)32 * HD; \
        _Pragma("unroll") \
        for (int jj = 0; jj < 8; ++jj) { vr0[jj] = t0[(long)jj * HD]; vr1[jj] = t1[(long)jj * HD]; } \
    } while (0)

    #define STAGE_WRITE() do { \
        bf16x8 w0, w1; \
        w0[0]=f2bf(kr00.x); w0[1]=f2bf(kr00.y); w0[2]=f2bf(kr00.z); w0[3]=f2bf(kr00.w); \
        w0[4]=f2bf(kr01.x); w0[5]=f2bf(kr01.y); w0[6]=f2bf(kr01.z); w0[7]=f2bf(kr01.w); \
        w1[0]=f2bf(kr10.x); w1[1]=f2bf(kr10.y); w1[2]=f2bf(kr10.z); w1[3]=f2bf(kr10.w); \
        w1[4]=f2bf(kr11.x); w1[5]=f2bf(kr11.y); w1[6]=f2bf(kr11.z); w1[7]=f2bf(kr11.w); \
        const int row0 = spos, row1 = spos + 32; \
        *(bf16x8*)((char*)Kl + ((row0 * 256 + sd8 * 16) ^ ((row0 & 7) << 4))) = w0; \
        *(bf16x8*)((char*)Kl + ((row1 * 256 + sd8 * 16) ^ ((row1 & 7) << 4))) = w1; \
        bf16x8 u0, u1; \
        _Pragma("unroll") \
        for (int jj = 0; jj < 8; ++jj) { u0[jj] = f2bf(vr0[jj]); u1[jj] = f2bf(vr1[jj]); } \
        *(bf16x8*)((char*)Vt2 + ((vd >> 4) * 2048 + (voct    ) * 256 + (vd & 15) * 16)) = u0; \
        *(bf16x8*)((char*)Vt2 + ((vd >> 4) * 2048 + (voct + 4) * 256 + (vd & 15) * 16)) = u1; \
    } while (0)

    STAGE_LOAD(0);
    for (int kp = 0; kp < 8; ++kp) {
        STAGE_WRITE();            // compiler inserts vmcnt waits for the reg loads
        __syncthreads();
        if (kp < 7) STAGE_LOAD(kp + 1);   // issue early: latency hides under compute

        const int kt0 = 2 * kp, kt1 = 2 * kp + 1;
        if (kt0 < npA) qs_tile(SA,  qtA, kt0 * 32, 0, (const char*)Kl, (const char*)Vt2, pbase, g16, li);
        if (kt1 < npA) qs_tile(SA,  qtA, kt1 * 32, 1, (const char*)Kl, (const char*)Vt2, pbase, g16, li);
        if (kt0 < npB) qs_tile(SB2, qtB, kt0 * 32, 0, (const char*)Kl, (const char*)Vt2, pbase, g16, li);
        if (kt1 < npB) qs_tile(SB2, qtB, kt1 * 32, 1, (const char*)Kl, (const char*)Vt2, pbase, g16, li);

        __syncthreads();
    }

    qs_out(SA,  qtA, b, h, g16, li, out);
    qs_out(SB2, qtB, b, h, g16, li, out);
}

extern "C" void kernel_launch(void* const* d_in, const int* in_sizes, int n_in,
                              void* d_out, int out_size, void* d_ws, size_t ws_size,
                              hipStream_t stream) {
    const float* q  = (const float*)d_in[0];
    const float* k  = (const float*)d_in[1];
    const float* v  = (const float*)d_in[2];
    const float* kc = (const float*)d_in[3];
    const float* vc = (const float*)d_in[4];
    // d_in[5] = slot_mapping (derivable; caches are not outputs)
    const int* btab    = (const int*)d_in[6];
    const int* ctxlens = (const int*)d_in[7];
    float* outp = (float*)d_out;
    float* ws   = (float*)d_ws;   // 1024 partials x 136 floats = 557 KB

    gen_kernel <<<dim3(1024), dim3(256), 0, stream>>>(q, k, v, kc, vc, btab, ctxlens, ws);
    fill_kernel<<<dim3(256),  dim3(512), 0, stream>>>(q, k, v, ws, outp);
}